// Round 1
// baseline (757.457 us; speedup 1.0000x reference)
//
#include <hip/hip_runtime.h>

#define HW   256
#define HW2  (HW * HW)
#define CIN  64
#define COUT 64

// ---------------------------------------------------------------------------
// Kernel A: offset conv  off[b,m,r,c] = pb[m] + sum_{ic,dr,dc} pw[m,ic,dr,dc]
//                                        * x[b,ic,r-1+dr,c-1+dc]   (zero pad)
// One thread per (b,r,c), 18 accumulators. Weights are wave-uniform -> s_load.
// Block = 4 rows x 64 cols (lanes along c -> coalesced loads/stores).
// ---------------------------------------------------------------------------
__global__ __launch_bounds__(256) void offs_kernel(
    const float* __restrict__ x, const float* __restrict__ pw,
    const float* __restrict__ pb, float* __restrict__ off)
{
  const int b = blockIdx.y;
  const int bx = blockIdx.x;                 // 64 row-tiles * 4 col-tiles
  const int r = (bx >> 2) * 4 + (threadIdx.x >> 6);
  const int c = (bx & 3) * 64 + (threadIdx.x & 63);

  float acc[18];
#pragma unroll
  for (int m = 0; m < 18; ++m) acc[m] = pb[m];

  const float* xb = x + (size_t)b * CIN * HW2;
  for (int ic = 0; ic < CIN; ++ic) {
    const float* xc = xb + ic * HW2;
    float v[9];
#pragma unroll
    for (int dr = 0; dr < 3; ++dr) {
      const int rr = r - 1 + dr;
#pragma unroll
      for (int dc = 0; dc < 3; ++dc) {
        const int cc = c - 1 + dc;
        const bool ok = (rr >= 0) & (rr < HW) & (cc >= 0) & (cc < HW);
        v[dr * 3 + dc] = ok ? xc[rr * HW + cc] : 0.f;
      }
    }
#pragma unroll
    for (int m = 0; m < 18; ++m) {
      const float* wp = pw + ((m * CIN) + ic) * 9;   // uniform -> s_load
      float a = acc[m];
#pragma unroll
      for (int k = 0; k < 9; ++k) a = fmaf(wp[k], v[k], a);
      acc[m] = a;
    }
  }
#pragma unroll
  for (int m = 0; m < 18; ++m)
    off[(((size_t)b * 18 + m) * HW + r) * HW + c] = acc[m];
}

// ---------------------------------------------------------------------------
// Kernel B: fused bilinear sampling + 64x(64*9) contraction.
// Reference quirk (np.meshgrid 'xy'): at output (r,c) the sample base is
// (row = c+1, col = r+1). Lanes run along r so gather columns (~r) coalesce.
// Per thread: 36 corner (idx,weight) pairs in regs, then
//   for ic: 36 gathers -> 9 samples -> 576 FMAs (weights via scalar loads).
// ---------------------------------------------------------------------------
__global__ __launch_bounds__(256, 2) void deform_kernel(
    const float* __restrict__ x, const float* __restrict__ off,
    const float* __restrict__ w, float* __restrict__ out)
{
  const int b = blockIdx.y;
  const int bx = blockIdx.x;                 // 4 row-tiles * 64 col-tiles
  const int r = (bx & 3) * 64 + (threadIdx.x & 63);   // lanes along r
  const int c = (bx >> 2) * 4 + (threadIdx.x >> 6);

  int   qi[9][4];
  float qg[9][4];
  const float* ob = off + (size_t)b * 18 * HW2;
#pragma unroll
  for (int n = 0; n < 9; ++n) {
    const float ox = ob[(n * HW + r) * HW + c];
    const float oy = ob[((9 + n) * HW + r) * HW + c];
    // p = p0 + pn + off;  p0x = c+1 (transposed base!), pnx = n%3-1
    const float px = (float)(c + (n % 3)) + ox;      // row coord into padded
    const float py = (float)(r + (n / 3)) + oy;      // col coord into padded
    const float fx = floorf(px);
    const float fy = floorf(py);
    int ltx = (int)fx, lty = (int)fy;
    int rbx = ltx + 1, rby = lty + 1;
    ltx = min(max(ltx, 0), HW + 1); lty = min(max(lty, 0), HW + 1);
    rbx = min(max(rbx, 0), HW + 1); rby = min(max(rby, 0), HW + 1);
    const float pxc = fminf(fmaxf(px, 0.f), (float)(HW + 1));
    const float pyc = fminf(fmaxf(py, 0.f), (float)(HW + 1));
    const float wxl = 1.f + (float)ltx - pxc;        // (1+dx_lt)
    const float wxr = 1.f - ((float)rbx - pxc);      // (1-dx_rb)
    const float wyl = 1.f + (float)lty - pyc;        // (1+dy_lt)
    const float wyr = 1.f - ((float)rby - pyc);      // (1-dy_rb)
    const int   cx[4] = { ltx, rbx, ltx, rbx };
    const int   cy[4] = { lty, rby, rby, lty };
    const float cg[4] = { wxl * wyl, wxr * wyr, wxl * wyr, wxr * wyl };
#pragma unroll
    for (int k = 0; k < 4; ++k) {
      // padded image: border ring is zeros -> weight 0, idx into UNPADDED x
      const bool ok = (cx[k] >= 1) & (cx[k] <= HW) & (cy[k] >= 1) & (cy[k] <= HW);
      qi[n][k] = ok ? ((cx[k] - 1) * HW + (cy[k] - 1)) : 0;
      qg[n][k] = ok ? cg[k] : 0.f;
    }
  }

  float acc[COUT];
#pragma unroll
  for (int o = 0; o < COUT; ++o) acc[o] = 0.f;

  const float* xb = x + (size_t)b * CIN * HW2;
  for (int ic = 0; ic < CIN; ++ic) {
    const float* xc = xb + ic * HW2;
    float s[9];
#pragma unroll
    for (int n = 0; n < 9; ++n) {
      s[n] = qg[n][0] * xc[qi[n][0]] + qg[n][1] * xc[qi[n][1]]
           + qg[n][2] * xc[qi[n][2]] + qg[n][3] * xc[qi[n][3]];
    }
#pragma unroll
    for (int o = 0; o < COUT; ++o) {
      const float* wp = w + ((o * CIN) + ic) * 9;    // uniform -> s_load
      float a = acc[o];
#pragma unroll
      for (int n = 0; n < 9; ++n) a = fmaf(wp[n], s[n], a);
      acc[o] = a;
    }
  }

  float* outb = out + (size_t)b * COUT * HW2;
#pragma unroll
  for (int o = 0; o < COUT; ++o)
    outb[((size_t)o * HW + r) * HW + c] = acc[o];
}

// ---------------------------------------------------------------------------
extern "C" void kernel_launch(void* const* d_in, const int* in_sizes, int n_in,
                              void* d_out, int out_size, void* d_ws, size_t ws_size,
                              hipStream_t stream) {
  const float* x  = (const float*)d_in[0];   // (2,64,256,256)
  const float* pw = (const float*)d_in[1];   // (18,64,3,3)
  const float* pb = (const float*)d_in[2];   // (18,)
  const float* w  = (const float*)d_in[3];   // (64,64,3,3)
  float* out = (float*)d_out;                // (2,64,256,256)
  float* off = (float*)d_ws;                 // needs 2*18*256*256*4 = 9.44 MB

  dim3 grid(256, 2);
  offs_kernel<<<grid, 256, 0, stream>>>(x, pw, pb, off);
  deform_kernel<<<grid, 256, 0, stream>>>(x, off, w, out);
}